// Round 2
// baseline (1070.976 us; speedup 1.0000x reference)
//
#include <hip/hip_runtime.h>
#include <cstdint>
#include <cstddef>

typedef __bf16 bf16;
typedef __attribute__((ext_vector_type(8))) __bf16 bf16x8;
typedef __attribute__((ext_vector_type(4))) __bf16 bf16x4v;
typedef __attribute__((ext_vector_type(2))) __bf16 bf16x2;
typedef __attribute__((ext_vector_type(4))) float f32x4;
typedef __attribute__((ext_vector_type(2))) float f32x2;
typedef __attribute__((ext_vector_type(4))) int i32x4;

#define DIMN 4096
#define SEQ 512
#define MAXSEQ 2048
#define NHEAD 32
#define HD 128
#define NBH 128   // BSZ*NHEAD
#define MTOK 2048 // BSZ*SEQ

#define BM 128
#define BN 128
#define BK 32

// ---------------- async global->LDS (wave-uniform base + lane*16) ----------
__device__ __forceinline__ void gld_lds16(const void* g, void* l) {
  __builtin_amdgcn_global_load_lds(
      (const __attribute__((address_space(1))) unsigned int*)g,
      (__attribute__((address_space(3))) unsigned int*)l, 16, 0, 0);
}

// ---------------- m97-style bt-GEMM core: C[128,128] += A[128,K] * B[128,K]^T
// A row-major (lda), B row-major (ldb), contraction over fast dim of both.
__device__ __forceinline__ void gemm_core(const bf16* Ablk, const bf16* Bblk,
                                          int lda, int ldb, int kmax,
                                          f32x4 acc[4][4], bf16* As, bf16* Bs) {
  const int tid = threadIdx.x;
  const int wave = tid >> 6;
  const int lane = tid & 63;
  const int wm = (wave >> 1) * 64;
  const int wn = (wave & 1) * 64;
  const int lrow = lane & 15;
  const int lkq8 = (lane >> 4) * 8;

  // staging: wave w loads rows [32w,32w+32); lane -> (row = l>>2, 8-col chunk)
  const int srow = wave * 32 + (lane >> 2);
  const int scol = (lane & 3) * 8;
  const bf16* Ag = Ablk + (size_t)srow * lda + scol;
  const bf16* Bg = Bblk + (size_t)srow * ldb + scol;
  bf16* lA = As + wave * 32 * BK;  // wave-uniform LDS bases
  bf16* lB = Bs + wave * 32 * BK;

  for (int k0 = 0; k0 < kmax; k0 += BK) {
    __syncthreads();
    gld_lds16(Ag + k0, lA);
    gld_lds16(Ag + k0 + (size_t)16 * lda, lA + 16 * BK);
    gld_lds16(Bg + k0, lB);
    gld_lds16(Bg + k0 + (size_t)16 * ldb, lB + 16 * BK);
    __syncthreads();
    bf16x8 a[4], b[4];
#pragma unroll
    for (int i = 0; i < 4; ++i)
      a[i] = *(const bf16x8*)(As + (wm + i * 16 + lrow) * BK + lkq8);
#pragma unroll
    for (int i = 0; i < 4; ++i)
      b[i] = *(const bf16x8*)(Bs + (wn + i * 16 + lrow) * BK + lkq8);
#pragma unroll
    for (int mi = 0; mi < 4; ++mi)
#pragma unroll
      for (int ni = 0; ni < 4; ++ni)
        acc[mi][ni] = __builtin_amdgcn_mfma_f32_16x16x32_bf16(a[mi], b[ni], acc[mi][ni], 0, 0, 0);
  }
}

#define ACC_INIT(acc)                                   \
  f32x4 acc[4][4];                                      \
  _Pragma("unroll") for (int _i = 0; _i < 4; ++_i)      \
      _Pragma("unroll") for (int _j = 0; _j < 4; ++_j)  \
          acc[_i][_j] = f32x4{0.f, 0.f, 0.f, 0.f};

#define EPI_COORDS                                      \
  const int lane = threadIdx.x & 63;                    \
  const int wave = threadIdx.x >> 6;                    \
  const int wm = (wave >> 1) * 64, wn = (wave & 1) * 64;\
  const int cq = (lane >> 4) * 4, cc = lane & 15;

// ---------------- single weight dequant int32*scale -> bf16 ----------------
__global__ __launch_bounds__(256) void k_cvt_w1(const int* __restrict__ q,
                                                const float* __restrict__ s,
                                                bf16* __restrict__ w) {
  size_t i = ((size_t)blockIdx.x * 256 + threadIdx.x) * 4;
  i32x4 qi = *(const i32x4*)(q + i);
  float sc = s[i >> 12];
  bf16x4v o = {(bf16)((float)qi[0] * sc), (bf16)((float)qi[1] * sc),
               (bf16)((float)qi[2] * sc), (bf16)((float)qi[3] * sc)};
  *(bf16x4v*)(w + i) = o;
}

// ---------------- x fp32 -> bf16 -------------------------------------------
__global__ __launch_bounds__(256) void k_cvt_x(const float* __restrict__ x,
                                               bf16* __restrict__ xb) {
  size_t i = ((size_t)blockIdx.x * 256 + threadIdx.x) * 4;
  f32x4 v = *(const f32x4*)(x + i);
  bf16x4v o = {(bf16)v[0], (bf16)v[1], (bf16)v[2], (bf16)v[3]};
  *(bf16x4v*)(xb + i) = o;
}

// ---------------- projection GEMM with fused rotary epilogue ---------------
// mode 0: Q -> qkout bf16 (b,h,s,d), rotary
// mode 1: K -> qkout bf16 (b,h,s,d) + ckout fp32 (b,pos,h,d), rotary
// mode 2: V -> ckout fp32 (b,s,h,d), no rotary
__global__ __launch_bounds__(256, 2) void k_gemm_proj(
    const bf16* __restrict__ xb, const bf16* __restrict__ W, int mode,
    const float* __restrict__ fc, const float* __restrict__ fs,
    const int* __restrict__ idx, bf16* __restrict__ qkout,
    float* __restrict__ ckout) {
  __shared__ __align__(16) bf16 As[BM * BK];
  __shared__ __align__(16) bf16 Bs[BN * BK];
  const int n0 = blockIdx.x * BN;
  const int m0 = blockIdx.y * BM;
  ACC_INIT(acc);
  gemm_core(xb + (size_t)m0 * DIMN, W + (size_t)n0 * DIMN, DIMN, DIMN, DIMN, acc, As, Bs);
  EPI_COORDS;
  if (mode < 2) {
#pragma unroll
    for (int mi = 0; mi < 4; ++mi)
#pragma unroll
      for (int ni = 0; ni < 4; ++ni)
#pragma unroll
        for (int r = 0; r < 4; ++r) {
          const float v = acc[mi][ni][r];
          const float pv = __shfl_xor(v, 1, 64);  // partner: col^1, same row
          const int row = m0 + wm + mi * 16 + cq + r;
          const int col = n0 + wn + ni * 16 + cc;
          const int s = row & 511, b = row >> 9;
          const int hd = col & 127, h = col >> 7;
          const int d2 = hd >> 1;
          const float c = fc[s * 64 + d2], sn = fs[s * 64 + d2];
          // even col holds tr, odd col holds ti
          const float o = (col & 1) ? (pv * sn + v * c) : (v * c - pv * sn);
          qkout[(((size_t)(b * NHEAD + h)) * SEQ + s) * HD + hd] = (bf16)o;
          if (mode == 1) {
            const int pos = idx[s];
            ckout[((size_t)b * MAXSEQ + pos) * DIMN + col] = o;
          }
        }
  } else {
#pragma unroll
    for (int mi = 0; mi < 4; ++mi)
#pragma unroll
      for (int ni = 0; ni < 4; ++ni)
#pragma unroll
        for (int r = 0; r < 4; ++r) {
          const int row = m0 + wm + mi * 16 + cq + r;
          const int col = n0 + wn + ni * 16 + cc;
          const int s = row & 511, b = row >> 9;
          ckout[((size_t)b * MAXSEQ + s) * DIMN + col] = acc[mi][ni][r];
        }
  }
}

// ---------------- V transpose: cache_v (b,s,h,d) fp32 -> vt (b,h,d,s) bf16 -
__global__ __launch_bounds__(256) void k_vt(const float* __restrict__ cv,
                                            bf16* __restrict__ vt) {
  __shared__ float tile[32][129];
  const int s0 = blockIdx.x * 32;
  const int bh = blockIdx.y;
  const int b = bh >> 5, h = bh & 31;
  const int tid = threadIdx.x;
  const float* src = cv + (size_t)b * MAXSEQ * DIMN + h * HD;
#pragma unroll
  for (int p = 0; p < 16; ++p) {
    const int row = p * 2 + (tid >> 7);
    const int d = tid & 127;
    tile[row][d] = src[(size_t)(s0 + row) * DIMN + d];
  }
  __syncthreads();
  bf16* dst = vt + (size_t)bh * HD * SEQ;
#pragma unroll
  for (int c = 0; c < 16; ++c) {
    const int d = c * 8 + (tid >> 5);
    const int sl = tid & 31;
    dst[(size_t)d * SEQ + s0 + sl] = (bf16)tile[sl][d];
  }
}

// ---------------- QK^T for 64 heads: scores bf16, causal tile skip ---------
__global__ __launch_bounds__(256, 2) void k_gemm_qk(
    const bf16* __restrict__ qb, const bf16* __restrict__ kb,
    bf16* __restrict__ sc, int bh0) {
  const int n0 = blockIdx.x * BN;
  const int m0 = blockIdx.y * BM;
  if (n0 >= m0 + BM) return;  // fully masked tile
  const int z = blockIdx.z;   // local head slot [0,64)
  const int bh = bh0 + z;
  __shared__ __align__(16) bf16 As[BM * BK];
  __shared__ __align__(16) bf16 Bs[BN * BK];
  ACC_INIT(acc);
  gemm_core(qb + (size_t)bh * SEQ * HD + (size_t)m0 * HD,
            kb + (size_t)bh * SEQ * HD + (size_t)n0 * HD, HD, HD, HD, acc, As, Bs);
  EPI_COORDS;
  bf16* dst = sc + (size_t)z * SEQ * SEQ;
#pragma unroll
  for (int mi = 0; mi < 4; ++mi)
#pragma unroll
    for (int ni = 0; ni < 4; ++ni)
#pragma unroll
      for (int r = 0; r < 4; ++r) {
        const int row = m0 + wm + mi * 16 + cq + r;
        const int col = n0 + wn + ni * 16 + cc;
        dst[(size_t)row * SEQ + col] = (bf16)(acc[mi][ni][r] * 0.08838834764831845f);
      }
}

// ---------------- row softmax over 512 keys (wave per row), in-place -------
// grid covers 64*512 rows (one bh-half)
__global__ __launch_bounds__(256) void k_softmax(bf16* __restrict__ sc) {
  const int row = blockIdx.x * 4 + (threadIdx.x >> 6);
  const int lane = threadIdx.x & 63;
  const int q = row & 511;
  bf16* p = sc + (size_t)row * SEQ + lane * 8;
  bf16x8 v8 = *(const bf16x8*)p;
  float lv[8];
  float m = -3.0e38f;
#pragma unroll
  for (int j = 0; j < 8; ++j) {
    const int kj = lane * 8 + j;
    lv[j] = (kj <= q) ? (float)v8[j] : -3.0e38f;
    m = fmaxf(m, lv[j]);
  }
#pragma unroll
  for (int off = 32; off; off >>= 1) m = fmaxf(m, __shfl_xor(m, off, 64));
  float e[8];
  float sum = 0.f;
#pragma unroll
  for (int j = 0; j < 8; ++j) {
    e[j] = (lane * 8 + j <= q) ? __expf(lv[j] - m) : 0.f;
    sum += e[j];
  }
#pragma unroll
  for (int off = 32; off; off >>= 1) sum += __shfl_xor(sum, off, 64);
  const float r = 1.f / sum;
  bf16x8 o;
#pragma unroll
  for (int j = 0; j < 8; ++j) o[j] = (bf16)(e[j] * r);
  *(bf16x8*)p = o;
}

// ---------------- P @ V for 64 heads, causal K-bound -----------------------
__global__ __launch_bounds__(256, 2) void k_gemm_pv(
    const bf16* __restrict__ P, const bf16* __restrict__ vt,
    bf16* __restrict__ attn, int bh0) {
  const int m0 = blockIdx.y * BM;
  const int z = blockIdx.z;  // local head slot
  const int bh = bh0 + z;
  const int kmax = m0 + BM;  // P[q][k]==0 for k>q
  __shared__ __align__(16) bf16 As[BM * BK];
  __shared__ __align__(16) bf16 Bs[BN * BK];
  ACC_INIT(acc);
  gemm_core(P + (size_t)z * SEQ * SEQ + (size_t)m0 * SEQ,
            vt + (size_t)bh * HD * SEQ, SEQ, SEQ, kmax, acc, As, Bs);
  EPI_COORDS;
  const int b = bh >> 5, h = bh & 31;
#pragma unroll
  for (int mi = 0; mi < 4; ++mi)
#pragma unroll
    for (int ni = 0; ni < 4; ++ni)
#pragma unroll
      for (int r = 0; r < 4; ++r) {
        const int row = m0 + wm + mi * 16 + cq + r;
        const int col = wn + ni * 16 + cc;  // < 128
        attn[((size_t)(b * SEQ + row)) * DIMN + h * HD + col] = (bf16)acc[mi][ni][r];
      }
}

// ---------------- output projection ----------------------------------------
__global__ __launch_bounds__(256, 2) void k_gemm_out(
    const bf16* __restrict__ attn, const bf16* __restrict__ wo,
    float* __restrict__ out) {
  __shared__ __align__(16) bf16 As[BM * BK];
  __shared__ __align__(16) bf16 Bs[BN * BK];
  const int n0 = blockIdx.x * BN;
  const int m0 = blockIdx.y * BM;
  ACC_INIT(acc);
  gemm_core(attn + (size_t)m0 * DIMN, wo + (size_t)n0 * DIMN, DIMN, DIMN, DIMN, acc, As, Bs);
  EPI_COORDS;
#pragma unroll
  for (int mi = 0; mi < 4; ++mi)
#pragma unroll
    for (int ni = 0; ni < 4; ++ni)
#pragma unroll
      for (int r = 0; r < 4; ++r) {
        const int row = m0 + wm + mi * 16 + cq + r;
        const int col = n0 + wn + ni * 16 + cc;
        out[(size_t)row * DIMN + col] = acc[mi][ni][r];
      }
}

// ===========================================================================
extern "C" void kernel_launch(void* const* d_in, const int* in_sizes, int n_in,
                              void* d_out, int out_size, void* d_ws, size_t ws_size,
                              hipStream_t stream) {
  const float* x = (const float*)d_in[0];
  const float* fc = (const float*)d_in[1];
  const float* fs = (const float*)d_in[2];
  const int* idx = (const int*)d_in[4];
  const int* wq_q = (const int*)d_in[7];  const float* wq_s = (const float*)d_in[8];
  const int* wk_q = (const int*)d_in[9];  const float* wk_s = (const float*)d_in[10];
  const int* wv_q = (const int*)d_in[11]; const float* wv_s = (const float*)d_in[12];
  const int* wo_q = (const int*)d_in[13]; const float* wo_s = (const float*)d_in[14];

  float* out = (float*)d_out;                 // (4,512,4096) fp32, 32 MiB
  float* ck_out = out + 8388608;              // (4,2048,32,128) fp32, 128 MiB
  float* cv_out = ck_out + 33554432;          // (4,2048,32,128) fp32, 128 MiB

  // workspace layout — peak 96 MiB
  char* ws = (char*)d_ws;
  bf16* W   = (bf16*)(ws + 0);                //  0..32 MiB, reused 4x
  bf16* XBF = (bf16*)(ws + 33554432ull);      // 32..48 MiB
  bf16* QBF = (bf16*)(ws + 50331648ull);      // 48..64 MiB (b,h,s,d)
  bf16* KBF = (bf16*)(ws + 67108864ull);      // 64..80 MiB (b,h,s,d)
  bf16* VTB = (bf16*)(ws + 83886080ull);      // 80..96 MiB (b,h,d,s)
  bf16* ATTN = (bf16*)(ws + 33554432ull);     // overlays XBF (dead after V GEMM)
  bf16* SC = (bf16*)d_out;                    // 32 MiB scores scratch in out region

  // 1. zero cache_k + cache_v (rows >= 512 must be zero; rest overwritten)
  hipMemsetAsync(ck_out, 0, 268435456ull, stream);
  // 2. x -> bf16
  k_cvt_x<<<dim3(8192), 256, 0, stream>>>(x, XBF);
  // 3. Q projection (+rotary)
  k_cvt_w1<<<dim3(16384), 256, 0, stream>>>(wq_q, wq_s, W);
  k_gemm_proj<<<dim3(32, 16), 256, 0, stream>>>(XBF, W, 0, fc, fs, idx, QBF, nullptr);
  // 4. K projection (+rotary, writes cache_k)
  k_cvt_w1<<<dim3(16384), 256, 0, stream>>>(wk_q, wk_s, W);
  k_gemm_proj<<<dim3(32, 16), 256, 0, stream>>>(XBF, W, 1, fc, fs, idx, KBF, ck_out);
  // 5. V projection (writes cache_v)
  k_cvt_w1<<<dim3(16384), 256, 0, stream>>>(wv_q, wv_s, W);
  k_gemm_proj<<<dim3(32, 16), 256, 0, stream>>>(XBF, W, 2, fc, fs, idx, nullptr, cv_out);
  // 6. V^T bf16 (b,h,d,s)
  k_vt<<<dim3(16, 128), 256, 0, stream>>>(cv_out, VTB);
  // 7. WO dequant (W slot free again)
  k_cvt_w1<<<dim3(16384), 256, 0, stream>>>(wo_q, wo_s, W);
  // 8. attention in two bh-halves, scores scratch = out region (32 MiB)
  for (int half = 0; half < 2; ++half) {
    const int bh0 = half * 64;
    k_gemm_qk<<<dim3(4, 4, 64), 256, 0, stream>>>(QBF, KBF, SC, bh0);
    k_softmax<<<dim3(8192), 256, 0, stream>>>(SC);
    k_gemm_pv<<<dim3(1, 4, 64), 256, 0, stream>>>(SC, VTB, ATTN, bh0);
  }
  // 9. out = attn @ WO^T (overwrites scores scratch)
  k_gemm_out<<<dim3(32, 16), 256, 0, stream>>>(ATTN, W, out);
  (void)in_sizes; (void)n_in; (void)out_size; (void)ws_size;
}

// Round 3
// 902.331 us; speedup vs baseline: 1.1869x; 1.1869x over previous
//
#include <hip/hip_runtime.h>
#include <cstdint>
#include <cstddef>

typedef __bf16 bf16;
typedef __attribute__((ext_vector_type(8))) __bf16 bf16x8;
typedef __attribute__((ext_vector_type(2))) __bf16 bf16x2;
typedef __attribute__((ext_vector_type(4))) float f32x4;
typedef __attribute__((ext_vector_type(2))) float f32x2;
typedef __attribute__((ext_vector_type(4))) int i32x4;

#define DIMN 4096
#define SEQ 512
#define MAXSEQ 2048
#define NHEAD 32
#define HD 128
#define NBH 128
#define MTOK 2048

#define BM 128
#define BN 128
#define BK 32   // bf16 core: 32 elems = 64 B rows
#define BKI 64  // i8 core:   64 elems = 64 B rows

// ---------------- async global->LDS (wave-uniform base + lane*16) ----------
__device__ __forceinline__ void gld_lds16(const void* g, void* l) {
  __builtin_amdgcn_global_load_lds(
      (const __attribute__((address_space(1))) unsigned int*)g,
      (__attribute__((address_space(3))) unsigned int*)l, 16, 0, 0);
}

// ---------------- bf16 bt-GEMM core (m97 lineage) --------------------------
__device__ __forceinline__ void gemm_core(const bf16* Ablk, const bf16* Bblk,
                                          int lda, int ldb, int kmax,
                                          f32x4 acc[4][4], bf16* As, bf16* Bs) {
  const int tid = threadIdx.x;
  const int wave = tid >> 6;
  const int lane = tid & 63;
  const int wm = (wave >> 1) * 64;
  const int wn = (wave & 1) * 64;
  const int lrow = lane & 15;
  const int lkq8 = (lane >> 4) * 8;
  const int srow = wave * 32 + (lane >> 2);
  const int scol = (lane & 3) * 8;
  const bf16* Ag = Ablk + (size_t)srow * lda + scol;
  const bf16* Bg = Bblk + (size_t)srow * ldb + scol;
  bf16* lA = As + wave * 32 * BK;
  bf16* lB = Bs + wave * 32 * BK;

  for (int k0 = 0; k0 < kmax; k0 += BK) {
    __syncthreads();
    gld_lds16(Ag + k0, lA);
    gld_lds16(Ag + k0 + (size_t)16 * lda, lA + 16 * BK);
    gld_lds16(Bg + k0, lB);
    gld_lds16(Bg + k0 + (size_t)16 * ldb, lB + 16 * BK);
    __syncthreads();
    bf16x8 a[4], b[4];
#pragma unroll
    for (int i = 0; i < 4; ++i)
      a[i] = *(const bf16x8*)(As + (wm + i * 16 + lrow) * BK + lkq8);
#pragma unroll
    for (int i = 0; i < 4; ++i)
      b[i] = *(const bf16x8*)(Bs + (wn + i * 16 + lrow) * BK + lkq8);
#pragma unroll
    for (int mi = 0; mi < 4; ++mi)
#pragma unroll
      for (int ni = 0; ni < 4; ++ni)
        acc[mi][ni] = __builtin_amdgcn_mfma_f32_16x16x32_bf16(a[mi], b[ni], acc[mi][ni], 0, 0, 0);
  }
}

// ---------------- int8 bt-GEMM core: same structure, K=64/iter -------------
__device__ __forceinline__ void gemm_core_i8(const char* Ablk, const char* Bblk,
                                             int lda, int ldb, int kmax,
                                             i32x4 acc[4][4], char* As, char* Bs) {
  const int tid = threadIdx.x;
  const int wave = tid >> 6;
  const int lane = tid & 63;
  const int wm = (wave >> 1) * 64;
  const int wn = (wave & 1) * 64;
  const int lrow = lane & 15;
  const int lkq16 = (lane >> 4) * 16;  // 16 contiguous int8 per lane
  const int srow = wave * 32 + (lane >> 2);
  const int scol = (lane & 3) * 16;
  const char* Ag = Ablk + (size_t)srow * lda + scol;
  const char* Bg = Bblk + (size_t)srow * ldb + scol;
  char* lA = As + wave * 32 * BKI;
  char* lB = Bs + wave * 32 * BKI;

  for (int k0 = 0; k0 < kmax; k0 += BKI) {
    __syncthreads();
    gld_lds16(Ag + k0, lA);
    gld_lds16(Ag + k0 + (size_t)16 * lda, lA + 16 * BKI);
    gld_lds16(Bg + k0, lB);
    gld_lds16(Bg + k0 + (size_t)16 * ldb, lB + 16 * BKI);
    __syncthreads();
    i32x4 a[4], b[4];
#pragma unroll
    for (int i = 0; i < 4; ++i)
      a[i] = *(const i32x4*)(As + (wm + i * 16 + lrow) * BKI + lkq16);
#pragma unroll
    for (int i = 0; i < 4; ++i)
      b[i] = *(const i32x4*)(Bs + (wn + i * 16 + lrow) * BKI + lkq16);
#pragma unroll
    for (int mi = 0; mi < 4; ++mi)
#pragma unroll
      for (int ni = 0; ni < 4; ++ni)
        acc[mi][ni] = __builtin_amdgcn_mfma_i32_16x16x64_i8(a[mi], b[ni], acc[mi][ni], 0, 0, 0);
  }
}

#define ACC_INIT_F(acc)                                 \
  f32x4 acc[4][4];                                      \
  _Pragma("unroll") for (int _i = 0; _i < 4; ++_i)      \
      _Pragma("unroll") for (int _j = 0; _j < 4; ++_j)  \
          acc[_i][_j] = f32x4{0.f, 0.f, 0.f, 0.f};

#define ACC_INIT_I(acc)                                 \
  i32x4 acc[4][4];                                      \
  _Pragma("unroll") for (int _i = 0; _i < 4; ++_i)      \
      _Pragma("unroll") for (int _j = 0; _j < 4; ++_j)  \
          acc[_i][_j] = i32x4{0, 0, 0, 0};

#define EPI_COORDS                                      \
  const int lane = threadIdx.x & 63;                    \
  const int wave = threadIdx.x >> 6;                    \
  const int wm = (wave >> 1) * 64, wn = (wave & 1) * 64;\
  const int cq = (lane >> 4) * 4, cc = lane & 15;

// ---------------- weights int32 -> packed int8 (exact) ---------------------
__global__ __launch_bounds__(256) void k_cvt_w8(
    const int* __restrict__ q0, const int* __restrict__ q1,
    const int* __restrict__ q2, const int* __restrict__ q3,
    char* __restrict__ w8) {
  const int* q = (blockIdx.y == 0) ? q0 : (blockIdx.y == 1) ? q1
               : (blockIdx.y == 2) ? q2 : q3;
  char* w = w8 + (size_t)blockIdx.y * 16777216ull;
  size_t i = ((size_t)blockIdx.x * 256 + threadIdx.x) * 16;
  const i32x4* qp = (const i32x4*)(q + i);
  i32x4 a = qp[0], b = qp[1], c = qp[2], d = qp[3];
  i32x4 o;
  o[0] = (a[0] & 255) | ((a[1] & 255) << 8) | ((a[2] & 255) << 16) | (a[3] << 24);
  o[1] = (b[0] & 255) | ((b[1] & 255) << 8) | ((b[2] & 255) << 16) | (b[3] << 24);
  o[2] = (c[0] & 255) | ((c[1] & 255) << 8) | ((c[2] & 255) << 16) | (c[3] << 24);
  o[3] = (d[0] & 255) | ((d[1] & 255) << 8) | ((d[2] & 255) << 16) | (d[3] << 24);
  *(i32x4*)(w + i) = o;
}

// ---------------- x fp32 -> int8, per-row absmax scale ---------------------
__global__ __launch_bounds__(256) void k_quant_x(const float* __restrict__ x,
                                                 char* __restrict__ x8,
                                                 float* __restrict__ xs) {
  __shared__ float red[4];
  const int row = blockIdx.x, tid = threadIdx.x;
  const float* src = x + (size_t)row * DIMN + tid * 16;
  f32x4 v[4];
#pragma unroll
  for (int j = 0; j < 4; ++j) v[j] = ((const f32x4*)src)[j];
  float am = 0.f;
#pragma unroll
  for (int j = 0; j < 4; ++j)
#pragma unroll
    for (int e = 0; e < 4; ++e) am = fmaxf(am, fabsf(v[j][e]));
#pragma unroll
  for (int off = 32; off; off >>= 1) am = fmaxf(am, __shfl_xor(am, off, 64));
  if ((tid & 63) == 0) red[tid >> 6] = am;
  __syncthreads();
  am = fmaxf(fmaxf(red[0], red[1]), fmaxf(red[2], red[3]));
  const float inv = am > 0.f ? 127.f / am : 0.f;
  i32x4 o;
#pragma unroll
  for (int j = 0; j < 4; ++j) {
    int b0 = (int)rintf(v[j][0] * inv), b1 = (int)rintf(v[j][1] * inv);
    int b2 = (int)rintf(v[j][2] * inv), b3 = (int)rintf(v[j][3] * inv);
    o[j] = (b0 & 255) | ((b1 & 255) << 8) | ((b2 & 255) << 16) | (b3 << 24);
  }
  *(i32x4*)(x8 + (size_t)row * DIMN + tid * 16) = o;
  if (tid == 0) xs[row] = am * (1.f / 127.f);
}

// ---------------- attn bf16 -> int8, per-row absmax scale ------------------
__global__ __launch_bounds__(256) void k_quant_attn(const bf16* __restrict__ at,
                                                    char* __restrict__ a8,
                                                    float* __restrict__ as_) {
  __shared__ float red[4];
  const int row = blockIdx.x, tid = threadIdx.x;
  const bf16* src = at + (size_t)row * DIMN + tid * 16;
  bf16x8 h0 = ((const bf16x8*)src)[0], h1 = ((const bf16x8*)src)[1];
  float f[16];
#pragma unroll
  for (int j = 0; j < 8; ++j) { f[j] = (float)h0[j]; f[8 + j] = (float)h1[j]; }
  float am = 0.f;
#pragma unroll
  for (int j = 0; j < 16; ++j) am = fmaxf(am, fabsf(f[j]));
#pragma unroll
  for (int off = 32; off; off >>= 1) am = fmaxf(am, __shfl_xor(am, off, 64));
  if ((tid & 63) == 0) red[tid >> 6] = am;
  __syncthreads();
  am = fmaxf(fmaxf(red[0], red[1]), fmaxf(red[2], red[3]));
  const float inv = am > 0.f ? 127.f / am : 0.f;
  i32x4 o;
#pragma unroll
  for (int j = 0; j < 4; ++j) {
    int b0 = (int)rintf(f[j * 4 + 0] * inv), b1 = (int)rintf(f[j * 4 + 1] * inv);
    int b2 = (int)rintf(f[j * 4 + 2] * inv), b3 = (int)rintf(f[j * 4 + 3] * inv);
    o[j] = (b0 & 255) | ((b1 & 255) << 8) | ((b2 & 255) << 16) | (b3 << 24);
  }
  *(i32x4*)(a8 + (size_t)row * DIMN + tid * 16) = o;
  if (tid == 0) as_[row] = am * (1.f / 127.f);
}

// ---------------- QKV projection (i8) with fused dequant+rotary ------------
// z=0: Q -> qbf bf16 (b,h,s,d); z=1: K -> kbf + ck fp32; z=2: V -> cv fp32
__global__ __launch_bounds__(256, 2) void k_gemm_qkv8(
    const char* __restrict__ X8, const char* __restrict__ W8,
    const float* __restrict__ xs, const float* __restrict__ sq,
    const float* __restrict__ sk, const float* __restrict__ sv,
    const float* __restrict__ fc, const float* __restrict__ fs,
    const int* __restrict__ idx, bf16* __restrict__ qbf,
    bf16* __restrict__ kbf, float* __restrict__ ck, float* __restrict__ cv) {
  __shared__ __align__(16) char As[BM * BKI];
  __shared__ __align__(16) char Bs[BN * BKI];
  const int n0 = blockIdx.x * BN;
  const int m0 = blockIdx.y * BM;
  const int z = blockIdx.z;
  const char* W = W8 + (size_t)z * 16777216ull;
  const float* sw = (z == 0) ? sq : (z == 1) ? sk : sv;
  ACC_INIT_I(acc);
  gemm_core_i8(X8 + (size_t)m0 * DIMN, W + (size_t)n0 * DIMN, DIMN, DIMN, DIMN, acc, As, Bs);
  EPI_COORDS;
  if (z < 2) {
    bf16* dst = (z == 0) ? qbf : kbf;
#pragma unroll
    for (int mi = 0; mi < 4; ++mi)
#pragma unroll
      for (int ni = 0; ni < 4; ++ni)
#pragma unroll
        for (int r = 0; r < 4; ++r) {
          const int row = m0 + wm + mi * 16 + cq + r;
          const int col = n0 + wn + ni * 16 + cc;
          const float v = (float)acc[mi][ni][r] * xs[row] * sw[col];
          const float pv = __shfl_xor(v, 1, 64);  // partner col^1, same row
          const int s = row & 511, b = row >> 9;
          const int hd = col & 127, h = col >> 7;
          const int d2 = hd >> 1;
          const float c = fc[s * 64 + d2], sn = fs[s * 64 + d2];
          const float o = (col & 1) ? (pv * sn + v * c) : (v * c - pv * sn);
          dst[(((size_t)(b * NHEAD + h)) * SEQ + s) * HD + hd] = (bf16)o;
          if (z == 1) {
            const int pos = idx[s];
            ck[((size_t)b * MAXSEQ + pos) * DIMN + col] = o;
          }
        }
  } else {
#pragma unroll
    for (int mi = 0; mi < 4; ++mi)
#pragma unroll
      for (int ni = 0; ni < 4; ++ni)
#pragma unroll
        for (int r = 0; r < 4; ++r) {
          const int row = m0 + wm + mi * 16 + cq + r;
          const int col = n0 + wn + ni * 16 + cc;
          const int s = row & 511, b = row >> 9;
          cv[((size_t)b * MAXSEQ + s) * DIMN + col] =
              (float)acc[mi][ni][r] * xs[row] * sw[col];
        }
  }
}

// ---------------- V transpose: cache_v (b,s,h,d) fp32 -> vt (b,h,d,s) bf16 -
__global__ __launch_bounds__(256) void k_vt(const float* __restrict__ cv,
                                            bf16* __restrict__ vt) {
  __shared__ float tile[32][129];
  const int s0 = blockIdx.x * 32;
  const int bh = blockIdx.y;
  const int b = bh >> 5, h = bh & 31;
  const int tid = threadIdx.x;
  const float* src = cv + (size_t)b * MAXSEQ * DIMN + h * HD;
#pragma unroll
  for (int p = 0; p < 16; ++p) {
    const int row = p * 2 + (tid >> 7);
    const int d = tid & 127;
    tile[row][d] = src[(size_t)(s0 + row) * DIMN + d];
  }
  __syncthreads();
  bf16* dst = vt + (size_t)bh * HD * SEQ;
#pragma unroll
  for (int c = 0; c < 16; ++c) {
    const int d = c * 8 + (tid >> 5);
    const int sl = tid & 31;
    dst[(size_t)d * SEQ + s0 + sl] = (bf16)tile[sl][d];
  }
}

// ---------------- QK^T: scores bf16, causal tile skip ----------------------
__global__ __launch_bounds__(256, 2) void k_gemm_qk(
    const bf16* __restrict__ qb, const bf16* __restrict__ kb,
    bf16* __restrict__ sc) {
  const int n0 = blockIdx.x * BN;
  const int m0 = blockIdx.y * BM;
  if (n0 >= m0 + BM) return;
  const int bh = blockIdx.z;
  __shared__ __align__(16) bf16 As[BM * BK];
  __shared__ __align__(16) bf16 Bs[BN * BK];
  ACC_INIT_F(acc);
  gemm_core(qb + (size_t)bh * SEQ * HD + (size_t)m0 * HD,
            kb + (size_t)bh * SEQ * HD + (size_t)n0 * HD, HD, HD, HD, acc, As, Bs);
  EPI_COORDS;
  bf16* dst = sc + (size_t)bh * SEQ * SEQ;
#pragma unroll
  for (int mi = 0; mi < 4; ++mi)
#pragma unroll
    for (int ni = 0; ni < 4; ++ni)
#pragma unroll
      for (int r = 0; r < 4; ++r) {
        const int row = m0 + wm + mi * 16 + cq + r;
        const int col = n0 + wn + ni * 16 + cc;
        dst[(size_t)row * SEQ + col] = (bf16)(acc[mi][ni][r] * 0.08838834764831845f);
      }
}

// ---------------- row softmax, in-place ------------------------------------
__global__ __launch_bounds__(256) void k_softmax(bf16* __restrict__ sc) {
  const int row = blockIdx.x * 4 + (threadIdx.x >> 6);
  const int lane = threadIdx.x & 63;
  const int q = row & 511;
  bf16* p = sc + (size_t)row * SEQ + lane * 8;
  bf16x8 v8 = *(const bf16x8*)p;
  float lv[8];
  float m = -3.0e38f;
#pragma unroll
  for (int j = 0; j < 8; ++j) {
    const int kj = lane * 8 + j;
    lv[j] = (kj <= q) ? (float)v8[j] : -3.0e38f;
    m = fmaxf(m, lv[j]);
  }
#pragma unroll
  for (int off = 32; off; off >>= 1) m = fmaxf(m, __shfl_xor(m, off, 64));
  float e[8];
  float sum = 0.f;
#pragma unroll
  for (int j = 0; j < 8; ++j) {
    e[j] = (lane * 8 + j <= q) ? __expf(lv[j] - m) : 0.f;
    sum += e[j];
  }
#pragma unroll
  for (int off = 32; off; off >>= 1) sum += __shfl_xor(sum, off, 64);
  const float r = 1.f / sum;
  bf16x8 o;
#pragma unroll
  for (int j = 0; j < 8; ++j) o[j] = (bf16)(e[j] * r);
  *(bf16x8*)p = o;
}

// ---------------- P @ V, causal K-bound ------------------------------------
__global__ __launch_bounds__(256, 2) void k_gemm_pv(
    const bf16* __restrict__ P, const bf16* __restrict__ vt,
    bf16* __restrict__ attn) {
  const int m0 = blockIdx.y * BM;
  const int bh = blockIdx.z;
  const int kmax = m0 + BM;
  __shared__ __align__(16) bf16 As[BM * BK];
  __shared__ __align__(16) bf16 Bs[BN * BK];
  ACC_INIT_F(acc);
  gemm_core(P + (size_t)bh * SEQ * SEQ + (size_t)m0 * SEQ,
            vt + (size_t)bh * HD * SEQ, SEQ, SEQ, kmax, acc, As, Bs);
  EPI_COORDS;
  const int b = bh >> 5, h = bh & 31;
#pragma unroll
  for (int mi = 0; mi < 4; ++mi)
#pragma unroll
    for (int ni = 0; ni < 4; ++ni)
#pragma unroll
      for (int r = 0; r < 4; ++r) {
        const int row = m0 + wm + mi * 16 + cq + r;
        const int col = wn + ni * 16 + cc;  // < 128
        attn[((size_t)(b * SEQ + row)) * DIMN + h * HD + col] = (bf16)acc[mi][ni][r];
      }
}

// ---------------- output projection (i8) -----------------------------------
__global__ __launch_bounds__(256, 2) void k_gemm_out8(
    const char* __restrict__ A8, const char* __restrict__ WO8,
    const float* __restrict__ as_, const float* __restrict__ so,
    float* __restrict__ out) {
  __shared__ __align__(16) char As[BM * BKI];
  __shared__ __align__(16) char Bs[BN * BKI];
  const int n0 = blockIdx.x * BN;
  const int m0 = blockIdx.y * BM;
  ACC_INIT_I(acc);
  gemm_core_i8(A8 + (size_t)m0 * DIMN, WO8 + (size_t)n0 * DIMN, DIMN, DIMN, DIMN, acc, As, Bs);
  EPI_COORDS;
#pragma unroll
  for (int mi = 0; mi < 4; ++mi)
#pragma unroll
    for (int ni = 0; ni < 4; ++ni)
#pragma unroll
      for (int r = 0; r < 4; ++r) {
        const int row = m0 + wm + mi * 16 + cq + r;
        const int col = n0 + wn + ni * 16 + cc;
        out[(size_t)row * DIMN + col] = (float)acc[mi][ni][r] * as_[row] * so[col];
      }
}

// ===========================================================================
extern "C" void kernel_launch(void* const* d_in, const int* in_sizes, int n_in,
                              void* d_out, int out_size, void* d_ws, size_t ws_size,
                              hipStream_t stream) {
  const float* x = (const float*)d_in[0];
  const float* fc = (const float*)d_in[1];
  const float* fs = (const float*)d_in[2];
  const int* idx = (const int*)d_in[4];
  const int* wq_q = (const int*)d_in[7];  const float* wq_s = (const float*)d_in[8];
  const int* wk_q = (const int*)d_in[9];  const float* wk_s = (const float*)d_in[10];
  const int* wv_q = (const int*)d_in[11]; const float* wv_s = (const float*)d_in[12];
  const int* wo_q = (const int*)d_in[13]; const float* wo_s = (const float*)d_in[14];

  float* out = (float*)d_out;                 // (4,512,4096) fp32
  float* ck_out = out + 8388608;              // (4,2048,32,128) fp32
  float* cv_out = ck_out + 33554432;          // (4,2048,32,128) fp32

  // workspace layout (~235 MiB peak; ws >= 1 GiB per harness poison fills)
  char* ws = (char*)d_ws;
  char* W8   = ws;                            // 0..64 MiB: WQ8,WK8,WV8,WO8
  char* X8   = ws + 67108864ull;              // 8.4 MiB
  float* XS  = (float*)(ws + 75497472ull);    // 2048 f
  float* AS  = (float*)(ws + 75513856ull);    // 2048 f
  bf16* QBF  = (bf16*)(ws + 83886080ull);     // (b,h,s,d) 16.8 MiB
  bf16* KBF  = (bf16*)(ws + 100663296ull);
  bf16* VTB  = (bf16*)(ws + 117440512ull);    // (b,h,d,s)
  bf16* ATTN = (bf16*)(ws + 134217728ull);
  char* A8   = ws + 150994944ull;             // 8.4 MiB
  bf16* SC   = (bf16*)(ws + 167772160ull);    // 64 MiB scores

  // 1. zero only cache rows >= 512 (rows < 512 are fully written)
  for (int b = 0; b < 4; ++b) {
    hipMemsetAsync(ck_out + ((size_t)b * MAXSEQ + SEQ) * DIMN, 0, 25165824ull, stream);
    hipMemsetAsync(cv_out + ((size_t)b * MAXSEQ + SEQ) * DIMN, 0, 25165824ull, stream);
  }
  // 2. weights -> packed int8 (exact), x -> int8 + per-row scale
  k_cvt_w8<<<dim3(4096, 4), 256, 0, stream>>>(wq_q, wk_q, wv_q, wo_q, W8);
  k_quant_x<<<dim3(2048), 256, 0, stream>>>(x, X8, XS);
  // 3. QKV projections (i8), fused dequant+rotary epilogue
  k_gemm_qkv8<<<dim3(32, 16, 3), 256, 0, stream>>>(
      X8, W8, XS, wq_s, wk_s, wv_s, fc, fs, idx, QBF, KBF, ck_out, cv_out);
  // 4. V^T bf16 (b,h,d,s)
  k_vt<<<dim3(16, 128), 256, 0, stream>>>(cv_out, VTB);
  // 5. attention
  k_gemm_qk<<<dim3(4, 4, 128), 256, 0, stream>>>(QBF, KBF, SC);
  k_softmax<<<dim3(16384), 256, 0, stream>>>(SC);
  k_gemm_pv<<<dim3(1, 4, 128), 256, 0, stream>>>(SC, VTB, ATTN);
  // 6. attn -> int8, output projection (i8)
  k_quant_attn<<<dim3(2048), 256, 0, stream>>>(ATTN, A8, AS);
  k_gemm_out8<<<dim3(32, 16), 256, 0, stream>>>(A8, W8 + 50331648ull, AS, wo_s, out);
  (void)in_sizes; (void)n_in; (void)out_size; (void)ws_size;
}

// Round 4
// 873.720 us; speedup vs baseline: 1.2258x; 1.0327x over previous
//
#include <hip/hip_runtime.h>
#include <cstdint>
#include <cstddef>

typedef __bf16 bf16;
typedef __attribute__((ext_vector_type(8))) __bf16 bf16x8;
typedef __attribute__((ext_vector_type(2))) __bf16 bf16x2;
typedef __attribute__((ext_vector_type(4))) float f32x4;
typedef __attribute__((ext_vector_type(2))) float f32x2;
typedef __attribute__((ext_vector_type(4))) int i32x4;

#define DIMN 4096
#define SEQ 512
#define MAXSEQ 2048
#define NHEAD 32
#define HD 128
#define NBH 128
#define MTOK 2048

#define BM 128
#define BN 128
#define BK 32    // bf16 core: 32 elems = 64 B rows
#define BKI 128  // i8 core:  128 elems = 128 B rows, XOR-swizzled

// ---------------- async global->LDS (wave-uniform base + lane*16) ----------
__device__ __forceinline__ void gld_lds16(const void* g, void* l) {
  __builtin_amdgcn_global_load_lds(
      (const __attribute__((address_space(1))) unsigned int*)g,
      (__attribute__((address_space(3))) unsigned int*)l, 16, 0, 0);
}

// ---------------- bf16 bt-GEMM core (m97 lineage, proven) ------------------
__device__ __forceinline__ void gemm_core(const bf16* Ablk, const bf16* Bblk,
                                          int lda, int ldb, int kmax,
                                          f32x4 acc[4][4], bf16* As, bf16* Bs) {
  const int tid = threadIdx.x;
  const int wave = tid >> 6;
  const int lane = tid & 63;
  const int wm = (wave >> 1) * 64;
  const int wn = (wave & 1) * 64;
  const int lrow = lane & 15;
  const int lkq8 = (lane >> 4) * 8;
  const int srow = wave * 32 + (lane >> 2);
  const int scol = (lane & 3) * 8;
  const bf16* Ag = Ablk + (size_t)srow * lda + scol;
  const bf16* Bg = Bblk + (size_t)srow * ldb + scol;
  bf16* lA = As + wave * 32 * BK;
  bf16* lB = Bs + wave * 32 * BK;

  for (int k0 = 0; k0 < kmax; k0 += BK) {
    __syncthreads();
    gld_lds16(Ag + k0, lA);
    gld_lds16(Ag + k0 + (size_t)16 * lda, lA + 16 * BK);
    gld_lds16(Bg + k0, lB);
    gld_lds16(Bg + k0 + (size_t)16 * ldb, lB + 16 * BK);
    __syncthreads();
    bf16x8 a[4], b[4];
#pragma unroll
    for (int i = 0; i < 4; ++i)
      a[i] = *(const bf16x8*)(As + (wm + i * 16 + lrow) * BK + lkq8);
#pragma unroll
    for (int i = 0; i < 4; ++i)
      b[i] = *(const bf16x8*)(Bs + (wn + i * 16 + lrow) * BK + lkq8);
#pragma unroll
    for (int mi = 0; mi < 4; ++mi)
#pragma unroll
      for (int ni = 0; ni < 4; ++ni)
        acc[mi][ni] = __builtin_amdgcn_mfma_f32_16x16x32_bf16(a[mi], b[ni], acc[mi][ni], 0, 0, 0);
  }
}

// ---------------- int8 bt-GEMM core, BKI=128, XOR-swizzled LDS -------------
// LDS row r slot c holds global chunk c ^ (r&7)  (16-B granules).
// Staging lane picks global chunk (lane&7)^(srow&7) so global_load_lds's
// fixed LDS slot (lane&7) receives the swizzled chunk. Fragment reads hit
// <=2-way bank conflicts (free) instead of 16-way for naive 128-B rows.
__device__ __forceinline__ void gemm_core_i8(const char* Ablk, const char* Bblk,
                                             int lda, int ldb, int kmax,
                                             i32x4 acc[4][4], char* As, char* Bs) {
  const int tid = threadIdx.x;
  const int wave = tid >> 6;
  const int lane = tid & 63;
  const int wm = (wave >> 1) * 64;
  const int wn = (wave & 1) * 64;
  const int lrow = lane & 15;
  const int q = lane >> 4;           // k-chunk quad within 64-elem window
  const int srow = wave * 32 + (lane >> 3);           // 8 rows / wave-load
  const int scol = (((lane & 7) ^ ((lane >> 3) & 7)) * 16);
  const char* Ag = Ablk + (size_t)srow * lda + scol;
  const char* Bg = Bblk + (size_t)srow * ldb + scol;
  char* lA = As + wave * 32 * BKI;
  char* lB = Bs + wave * 32 * BKI;

  for (int k0 = 0; k0 < kmax; k0 += BKI) {
    __syncthreads();
#pragma unroll
    for (int r = 0; r < 4; ++r) {
      gld_lds16(Ag + k0 + (size_t)(8 * r) * lda, lA + 8 * r * BKI);
      gld_lds16(Bg + k0 + (size_t)(8 * r) * ldb, lB + 8 * r * BKI);
    }
    __syncthreads();
#pragma unroll
    for (int kk = 0; kk < 2; ++kk) {
      i32x4 a[4], b[4];
#pragma unroll
      for (int i = 0; i < 4; ++i) {
        const int row = wm + i * 16 + lrow;
        const int slot = (kk * 4 + q) ^ (lrow & 7);
        a[i] = *(const i32x4*)(As + row * BKI + slot * 16);
      }
#pragma unroll
      for (int i = 0; i < 4; ++i) {
        const int row = wn + i * 16 + lrow;
        const int slot = (kk * 4 + q) ^ (lrow & 7);
        b[i] = *(const i32x4*)(Bs + row * BKI + slot * 16);
      }
#pragma unroll
      for (int mi = 0; mi < 4; ++mi)
#pragma unroll
        for (int ni = 0; ni < 4; ++ni)
          acc[mi][ni] = __builtin_amdgcn_mfma_i32_16x16x64_i8(a[mi], b[ni], acc[mi][ni], 0, 0, 0);
    }
  }
}

#define ACC_INIT_F(acc)                                 \
  f32x4 acc[4][4];                                      \
  _Pragma("unroll") for (int _i = 0; _i < 4; ++_i)      \
      _Pragma("unroll") for (int _j = 0; _j < 4; ++_j)  \
          acc[_i][_j] = f32x4{0.f, 0.f, 0.f, 0.f};

#define ACC_INIT_I(acc)                                 \
  i32x4 acc[4][4];                                      \
  _Pragma("unroll") for (int _i = 0; _i < 4; ++_i)      \
      _Pragma("unroll") for (int _j = 0; _j < 4; ++_j)  \
          acc[_i][_j] = i32x4{0, 0, 0, 0};

#define EPI_COORDS                                      \
  const int lane = threadIdx.x & 63;                    \
  const int wave = threadIdx.x >> 6;                    \
  const int wm = (wave >> 1) * 64, wn = (wave & 1) * 64;\
  const int cq = (lane >> 4) * 4, cc = lane & 15;

// ---------------- prep über-kernel: pack weights + quant x + zero caches ---
// blocks [0,16384): pack 4 weights int32->int8 (exact)
// blocks [16384,18432): x fp32 -> int8 + per-row scale
// blocks [18432,67584): zero cache rows >= 512 (8 regions x 24 MB)
__global__ __launch_bounds__(256) void k_prep(
    const int* __restrict__ q0, const int* __restrict__ q1,
    const int* __restrict__ q2, const int* __restrict__ q3,
    char* __restrict__ w8, const float* __restrict__ x,
    char* __restrict__ x8, float* __restrict__ xs,
    float* __restrict__ ck, float* __restrict__ cv) {
  __shared__ float red[4];
  const int bx = blockIdx.x;
  const int tid = threadIdx.x;
  if (bx < 16384) {
    const int w = bx >> 12;
    const int* q = (w == 0) ? q0 : (w == 1) ? q1 : (w == 2) ? q2 : q3;
    char* wp = w8 + (size_t)w * 16777216ull;
    size_t i = ((size_t)(bx & 4095) * 256 + tid) * 16;
    const i32x4* qp = (const i32x4*)(q + i);
    i32x4 a = qp[0], b = qp[1], c = qp[2], d = qp[3];
    i32x4 o;
    o[0] = (a[0] & 255) | ((a[1] & 255) << 8) | ((a[2] & 255) << 16) | (a[3] << 24);
    o[1] = (b[0] & 255) | ((b[1] & 255) << 8) | ((b[2] & 255) << 16) | (b[3] << 24);
    o[2] = (c[0] & 255) | ((c[1] & 255) << 8) | ((c[2] & 255) << 16) | (c[3] << 24);
    o[3] = (d[0] & 255) | ((d[1] & 255) << 8) | ((d[2] & 255) << 16) | (d[3] << 24);
    *(i32x4*)(wp + i) = o;
  } else if (bx < 18432) {
    const int row = bx - 16384;
    const float* src = x + (size_t)row * DIMN + tid * 16;
    f32x4 v[4];
#pragma unroll
    for (int j = 0; j < 4; ++j) v[j] = ((const f32x4*)src)[j];
    float am = 0.f;
#pragma unroll
    for (int j = 0; j < 4; ++j)
#pragma unroll
      for (int e = 0; e < 4; ++e) am = fmaxf(am, fabsf(v[j][e]));
#pragma unroll
    for (int off = 32; off; off >>= 1) am = fmaxf(am, __shfl_xor(am, off, 64));
    if ((tid & 63) == 0) red[tid >> 6] = am;
    __syncthreads();
    am = fmaxf(fmaxf(red[0], red[1]), fmaxf(red[2], red[3]));
    const float inv = am > 0.f ? 127.f / am : 0.f;
    i32x4 o;
#pragma unroll
    for (int j = 0; j < 4; ++j) {
      int b0 = (int)rintf(v[j][0] * inv), b1 = (int)rintf(v[j][1] * inv);
      int b2 = (int)rintf(v[j][2] * inv), b3 = (int)rintf(v[j][3] * inv);
      o[j] = (b0 & 255) | ((b1 & 255) << 8) | ((b2 & 255) << 16) | (b3 << 24);
    }
    *(i32x4*)(x8 + (size_t)row * DIMN + tid * 16) = o;
    if (tid == 0) xs[row] = am * (1.f / 127.f);
  } else {
    const int z = bx - 18432;
    const int region = z / 6144;  // 0..7: (b, ck/cv)
    const int zoff = z - region * 6144;
    const int b = region >> 1;
    float* base = (region & 1) ? cv : ck;
    char* p = (char*)(base + ((size_t)b * MAXSEQ + SEQ) * DIMN);
    *(f32x4*)(p + (size_t)zoff * 4096 + tid * 16) = f32x4{0.f, 0.f, 0.f, 0.f};
  }
}

// ---------------- attn bf16 -> int8, per-row absmax scale ------------------
__global__ __launch_bounds__(256) void k_quant_attn(const bf16* __restrict__ at,
                                                    char* __restrict__ a8,
                                                    float* __restrict__ as_) {
  __shared__ float red[4];
  const int row = blockIdx.x, tid = threadIdx.x;
  const bf16* src = at + (size_t)row * DIMN + tid * 16;
  bf16x8 h0 = ((const bf16x8*)src)[0], h1 = ((const bf16x8*)src)[1];
  float f[16];
#pragma unroll
  for (int j = 0; j < 8; ++j) { f[j] = (float)h0[j]; f[8 + j] = (float)h1[j]; }
  float am = 0.f;
#pragma unroll
  for (int j = 0; j < 16; ++j) am = fmaxf(am, fabsf(f[j]));
#pragma unroll
  for (int off = 32; off; off >>= 1) am = fmaxf(am, __shfl_xor(am, off, 64));
  if ((tid & 63) == 0) red[tid >> 6] = am;
  __syncthreads();
  am = fmaxf(fmaxf(red[0], red[1]), fmaxf(red[2], red[3]));
  const float inv = am > 0.f ? 127.f / am : 0.f;
  i32x4 o;
#pragma unroll
  for (int j = 0; j < 4; ++j) {
    int b0 = (int)rintf(f[j * 4 + 0] * inv), b1 = (int)rintf(f[j * 4 + 1] * inv);
    int b2 = (int)rintf(f[j * 4 + 2] * inv), b3 = (int)rintf(f[j * 4 + 3] * inv);
    o[j] = (b0 & 255) | ((b1 & 255) << 8) | ((b2 & 255) << 16) | (b3 << 24);
  }
  *(i32x4*)(a8 + (size_t)row * DIMN + tid * 16) = o;
  if (tid == 0) as_[row] = am * (1.f / 127.f);
}

// ---------------- QKV projection (i8) with fused dequant+rotary ------------
__global__ __launch_bounds__(256, 2) void k_gemm_qkv8(
    const char* __restrict__ X8, const char* __restrict__ W8,
    const float* __restrict__ xs, const float* __restrict__ sq,
    const float* __restrict__ sk, const float* __restrict__ sv,
    const float* __restrict__ fc, const float* __restrict__ fs,
    const int* __restrict__ idx, bf16* __restrict__ qbf,
    bf16* __restrict__ kbf, float* __restrict__ ck, float* __restrict__ cv) {
  __shared__ __align__(16) char As[BM * BKI];
  __shared__ __align__(16) char Bs[BN * BKI];
  const int n0 = blockIdx.x * BN;
  const int m0 = blockIdx.y * BM;
  const int z = blockIdx.z;
  const char* W = W8 + (size_t)z * 16777216ull;
  const float* sw = (z == 0) ? sq : (z == 1) ? sk : sv;
  ACC_INIT_I(acc);
  gemm_core_i8(X8 + (size_t)m0 * DIMN, W + (size_t)n0 * DIMN, DIMN, DIMN, DIMN, acc, As, Bs);
  EPI_COORDS;
  if (z < 2) {
    bf16* dst = (z == 0) ? qbf : kbf;
#pragma unroll
    for (int mi = 0; mi < 4; ++mi)
#pragma unroll
      for (int ni = 0; ni < 4; ++ni)
#pragma unroll
        for (int r = 0; r < 4; ++r) {
          const int row = m0 + wm + mi * 16 + cq + r;
          const int col = n0 + wn + ni * 16 + cc;
          const float v = (float)acc[mi][ni][r] * xs[row] * sw[col];
          const float pv = __shfl_xor(v, 1, 64);  // partner col^1, same row
          const int s = row & 511, b = row >> 9;
          const int hd = col & 127, h = col >> 7;
          const int d2 = hd >> 1;
          const float c = fc[s * 64 + d2], sn = fs[s * 64 + d2];
          const float o = (col & 1) ? (pv * sn + v * c) : (v * c - pv * sn);
          dst[(((size_t)(b * NHEAD + h)) * SEQ + s) * HD + hd] = (bf16)o;
          if (z == 1) {
            const int pos = idx[s];
            ck[((size_t)b * MAXSEQ + pos) * DIMN + col] = o;
          }
        }
  } else {
#pragma unroll
    for (int mi = 0; mi < 4; ++mi)
#pragma unroll
      for (int ni = 0; ni < 4; ++ni)
#pragma unroll
        for (int r = 0; r < 4; ++r) {
          const int row = m0 + wm + mi * 16 + cq + r;
          const int col = n0 + wn + ni * 16 + cc;
          const int s = row & 511, b = row >> 9;
          cv[((size_t)b * MAXSEQ + s) * DIMN + col] =
              (float)acc[mi][ni][r] * xs[row] * sw[col];
        }
  }
}

// ---------------- V transpose: cache_v (b,s<512,h,d) fp32 -> (b,h,d,s) bf16
__global__ __launch_bounds__(256) void k_vt(const float* __restrict__ cv,
                                            bf16* __restrict__ vt) {
  __shared__ float tile[32][129];
  const int s0 = blockIdx.x * 32;
  const int bh = blockIdx.y;
  const int b = bh >> 5, h = bh & 31;
  const int tid = threadIdx.x;
  const float* src = cv + (size_t)b * MAXSEQ * DIMN + h * HD;
#pragma unroll
  for (int p = 0; p < 16; ++p) {
    const int row = p * 2 + (tid >> 7);
    const int d = tid & 127;
    tile[row][d] = src[(size_t)(s0 + row) * DIMN + d];
  }
  __syncthreads();
  bf16* dst = vt + (size_t)bh * HD * SEQ;
#pragma unroll
  for (int c = 0; c < 16; ++c) {
    const int d = c * 8 + (tid >> 5);
    const int sl = tid & 31;
    dst[(size_t)d * SEQ + s0 + sl] = (bf16)tile[sl][d];
  }
}

// ---------------- QK^T: packed causal grid, scores bf16 --------------------
__constant__ int g_tm[10] = {0, 1, 1, 2, 2, 2, 3, 3, 3, 3};
__constant__ int g_tn[10] = {0, 0, 1, 0, 1, 2, 0, 1, 2, 3};

__global__ __launch_bounds__(256, 2) void k_gemm_qk(
    const bf16* __restrict__ qb, const bf16* __restrict__ kb,
    bf16* __restrict__ sc) {
  const int m0 = g_tm[blockIdx.x] * BM;
  const int n0 = g_tn[blockIdx.x] * BN;
  const int bh = blockIdx.z;
  __shared__ __align__(16) bf16 As[BM * BK];
  __shared__ __align__(16) bf16 Bs[BN * BK];
  ACC_INIT_F(acc);
  gemm_core(qb + (size_t)bh * SEQ * HD + (size_t)m0 * HD,
            kb + (size_t)bh * SEQ * HD + (size_t)n0 * HD, HD, HD, HD, acc, As, Bs);
  EPI_COORDS;
  bf16* dst = sc + (size_t)bh * SEQ * SEQ;
#pragma unroll
  for (int mi = 0; mi < 4; ++mi)
#pragma unroll
    for (int ni = 0; ni < 4; ++ni)
#pragma unroll
      for (int r = 0; r < 4; ++r) {
        const int row = m0 + wm + mi * 16 + cq + r;
        const int col = n0 + wn + ni * 16 + cc;
        dst[(size_t)row * SEQ + col] = (bf16)(acc[mi][ni][r] * 0.08838834764831845f);
      }
}

// ---------------- row softmax, in-place ------------------------------------
__global__ __launch_bounds__(256) void k_softmax(bf16* __restrict__ sc) {
  const int row = blockIdx.x * 4 + (threadIdx.x >> 6);
  const int lane = threadIdx.x & 63;
  const int q = row & 511;
  bf16* p = sc + (size_t)row * SEQ + lane * 8;
  bf16x8 v8 = *(const bf16x8*)p;
  float lv[8];
  float m = -3.0e38f;
#pragma unroll
  for (int j = 0; j < 8; ++j) {
    const int kj = lane * 8 + j;
    lv[j] = (kj <= q) ? (float)v8[j] : -3.0e38f;
    m = fmaxf(m, lv[j]);
  }
#pragma unroll
  for (int off = 32; off; off >>= 1) m = fmaxf(m, __shfl_xor(m, off, 64));
  float e[8];
  float sum = 0.f;
#pragma unroll
  for (int j = 0; j < 8; ++j) {
    e[j] = (lane * 8 + j <= q) ? __expf(lv[j] - m) : 0.f;
    sum += e[j];
  }
#pragma unroll
  for (int off = 32; off; off >>= 1) sum += __shfl_xor(sum, off, 64);
  const float r = 1.f / sum;
  bf16x8 o;
#pragma unroll
  for (int j = 0; j < 8; ++j) o[j] = (bf16)(e[j] * r);
  *(bf16x8*)p = o;
}

// ---------------- P @ V, causal K-bound ------------------------------------
__global__ __launch_bounds__(256, 2) void k_gemm_pv(
    const bf16* __restrict__ P, const bf16* __restrict__ vt,
    bf16* __restrict__ attn) {
  const int m0 = blockIdx.y * BM;
  const int bh = blockIdx.z;
  const int kmax = m0 + BM;
  __shared__ __align__(16) bf16 As[BM * BK];
  __shared__ __align__(16) bf16 Bs[BN * BK];
  ACC_INIT_F(acc);
  gemm_core(P + (size_t)bh * SEQ * SEQ + (size_t)m0 * SEQ,
            vt + (size_t)bh * HD * SEQ, SEQ, SEQ, kmax, acc, As, Bs);
  EPI_COORDS;
  const int b = bh >> 5, h = bh & 31;
#pragma unroll
  for (int mi = 0; mi < 4; ++mi)
#pragma unroll
    for (int ni = 0; ni < 4; ++ni)
#pragma unroll
      for (int r = 0; r < 4; ++r) {
        const int row = m0 + wm + mi * 16 + cq + r;
        const int col = wn + ni * 16 + cc;  // < 128
        attn[((size_t)(b * SEQ + row)) * DIMN + h * HD + col] = (bf16)acc[mi][ni][r];
      }
}

// ---------------- output projection (i8) -----------------------------------
__global__ __launch_bounds__(256, 2) void k_gemm_out8(
    const char* __restrict__ A8, const char* __restrict__ WO8,
    const float* __restrict__ as_, const float* __restrict__ so,
    float* __restrict__ out) {
  __shared__ __align__(16) char As[BM * BKI];
  __shared__ __align__(16) char Bs[BN * BKI];
  const int n0 = blockIdx.x * BN;
  const int m0 = blockIdx.y * BM;
  ACC_INIT_I(acc);
  gemm_core_i8(A8 + (size_t)m0 * DIMN, WO8 + (size_t)n0 * DIMN, DIMN, DIMN, DIMN, acc, As, Bs);
  EPI_COORDS;
#pragma unroll
  for (int mi = 0; mi < 4; ++mi)
#pragma unroll
    for (int ni = 0; ni < 4; ++ni)
#pragma unroll
      for (int r = 0; r < 4; ++r) {
        const int row = m0 + wm + mi * 16 + cq + r;
        const int col = n0 + wn + ni * 16 + cc;
        out[(size_t)row * DIMN + col] = (float)acc[mi][ni][r] * as_[row] * so[col];
      }
}

// ===========================================================================
extern "C" void kernel_launch(void* const* d_in, const int* in_sizes, int n_in,
                              void* d_out, int out_size, void* d_ws, size_t ws_size,
                              hipStream_t stream) {
  const float* x = (const float*)d_in[0];
  const float* fc = (const float*)d_in[1];
  const float* fs = (const float*)d_in[2];
  const int* idx = (const int*)d_in[4];
  const int* wq_q = (const int*)d_in[7];
  const int* wk_q = (const int*)d_in[9];
  const int* wv_q = (const int*)d_in[11];
  const int* wo_q = (const int*)d_in[13];
  const float* wq_s = (const float*)d_in[8];
  const float* wk_s = (const float*)d_in[10];
  const float* wv_s = (const float*)d_in[12];
  const float* wo_s = (const float*)d_in[14];

  float* out = (float*)d_out;                 // (4,512,4096) fp32
  float* ck_out = out + 8388608;              // (4,2048,32,128) fp32
  float* cv_out = ck_out + 33554432;          // (4,2048,32,128) fp32

  // workspace layout (~230 MiB; harness ws is ~1.15 GiB per poison fills)
  char* ws = (char*)d_ws;
  char* W8   = ws;                            // 64 MiB: WQ8,WK8,WV8,WO8
  char* X8   = ws + 67108864ull;              // 8.4 MiB
  float* XS  = (float*)(ws + 75497472ull);    // 2048 f
  float* AS  = (float*)(ws + 75513856ull);    // 2048 f
  bf16* QBF  = (bf16*)(ws + 83886080ull);     // (b,h,s,d) 16.8 MiB
  bf16* KBF  = (bf16*)(ws + 100663296ull);
  bf16* VTB  = (bf16*)(ws + 117440512ull);    // (b,h,d,s)
  bf16* ATTN = (bf16*)(ws + 134217728ull);
  char* A8   = ws + 150994944ull;             // 8.4 MiB
  bf16* SC   = (bf16*)(ws + 167772160ull);    // 64 MiB scores

  // 1. prep: pack weights (exact), quant x, zero cache rows >= 512
  k_prep<<<dim3(67584), 256, 0, stream>>>(wq_q, wk_q, wv_q, wo_q, W8, x, X8, XS,
                                          ck_out, cv_out);
  // 2. QKV projections (i8, BKI=128), fused dequant+rotary epilogue
  k_gemm_qkv8<<<dim3(32, 16, 3), 256, 0, stream>>>(
      X8, W8, XS, wq_s, wk_s, wv_s, fc, fs, idx, QBF, KBF, ck_out, cv_out);
  // 3. V^T bf16 (b,h,d,s)
  k_vt<<<dim3(16, 128), 256, 0, stream>>>(cv_out, VTB);
  // 4. attention
  k_gemm_qk<<<dim3(10, 1, 128), 256, 0, stream>>>(QBF, KBF, SC);
  k_softmax<<<dim3(16384), 256, 0, stream>>>(SC);
  k_gemm_pv<<<dim3(1, 4, 128), 256, 0, stream>>>(SC, VTB, ATTN);
  // 5. attn -> int8, output projection (i8, BKI=128)
  k_quant_attn<<<dim3(2048), 256, 0, stream>>>(ATTN, A8, AS);
  k_gemm_out8<<<dim3(32, 16), 256, 0, stream>>>(A8, W8 + 50331648ull, AS, wo_s, out);
  (void)in_sizes; (void)n_in; (void)out_size; (void)ws_size;
}